// Round 1
// baseline (678.086 us; speedup 1.0000x reference)
//
#include <hip/hip_runtime.h>

#define N_ROWS 32768
#define HDIM 1024
#define NCLS 1000
#define CPAD 1024
#define NOUT 1024
#define KK2 2048

typedef __attribute__((ext_vector_type(8))) unsigned short ushort8v;
typedef __attribute__((ext_vector_type(4))) unsigned short ushort4v;
typedef __attribute__((ext_vector_type(8))) _Float16 f16x8;
typedef __attribute__((ext_vector_type(4))) float f32x4;

__device__ inline unsigned short h_bits(_Float16 h) {
  union { _Float16 h; unsigned short u; } c; c.h = h; return c.u;
}

__device__ inline unsigned long long shfl_xor_u64(unsigned long long v, int m) {
  int lo = __shfl_xor((int)(unsigned)(v & 0xFFFFFFFFull), m, 64);
  int hi = __shfl_xor((int)(unsigned)(v >> 32), m, 64);
  return ((unsigned long long)(unsigned)hi << 32) | (unsigned)lo;
}

__global__ __launch_bounds__(256) void init_keys_kernel(unsigned long long* __restrict__ keys) {
  keys[(size_t)blockIdx.x * 256 + threadIdx.x] = 0ull;
}

// One block per (padded) anchor row: norm, scale by 1024/max(norm,eps), fp16 hi/lo split.
__global__ __launch_bounds__(256) void prep_anchors_kernel(
    const float* __restrict__ anchors, unsigned short* __restrict__ ash,
    unsigned short* __restrict__ asl, unsigned short* __restrict__ anh) {
  int c = blockIdx.x;
  int t = threadIdx.x;
  float v[4];
  float ss = 0.f;
  if (c < NCLS) {
    for (int i = 0; i < 4; i++) {
      v[i] = anchors[(size_t)c * HDIM + (i << 8) + t];
      ss += v[i] * v[i];
    }
  } else {
    v[0] = v[1] = v[2] = v[3] = 0.f;
  }
  for (int m = 1; m < 64; m <<= 1) ss += __shfl_xor(ss, m, 64);
  __shared__ float wsum[4];
  if ((t & 63) == 0) wsum[t >> 6] = ss;
  __syncthreads();
  float tot = wsum[0] + wsum[1] + wsum[2] + wsum[3];
  // scale by 1024 so the fp16 "lo" part stays clear of subnormals; argmax-invariant
  float scale = 1024.0f / fmaxf(sqrtf(tot), 1e-8f);
  for (int i = 0; i < 4; i++) {
    float x = v[i] * scale;
    _Float16 hi = (_Float16)x;
    float lo = x - (float)hi;
    size_t o = (size_t)c * HDIM + (i << 8) + t;
    ash[o] = h_bits(hi);
    asl[o] = h_bits((_Float16)lo);
    anh[o] = h_bits((_Float16)v[i]);
  }
}

// features fp32 -> fp16 hi + fp16 lo, vectorized
__global__ __launch_bounds__(256) void fsplit_kernel(const float* __restrict__ f,
    unsigned short* __restrict__ fh, unsigned short* __restrict__ fl) {
  size_t i = (size_t)blockIdx.x * 256 + threadIdx.x;
  float4 v = reinterpret_cast<const float4*>(f)[i];
  float xs[4] = {v.x, v.y, v.z, v.w};
  ushort4v h, l;
  for (int j = 0; j < 4; j++) {
    _Float16 hi = (_Float16)xs[j];
    float lo = xs[j] - (float)hi;
    h[j] = h_bits(hi);
    l[j] = h_bits((_Float16)lo);
  }
  reinterpret_cast<ushort4v*>(fh)[i] = h;
  reinterpret_cast<ushort4v*>(fl)[i] = l;
}

// W [2048,1024] fp32 row-major -> Wt [1024,2048] fp16 (k contiguous), via LDS transpose
__global__ __launch_bounds__(256) void wtrans_kernel(const float* __restrict__ W,
                                                     unsigned short* __restrict__ Wt) {
  __shared__ float tile[64][65];
  int kb = (blockIdx.x >> 4) << 6;  // 32 k-tiles
  int nb = (blockIdx.x & 15) << 6;  // 16 n-tiles
  int t = threadIdx.x;
  int tc = t & 63, tr = t >> 6;
  for (int i = 0; i < 16; i++) {
    int r = (i << 2) + tr;
    tile[r][tc] = W[(size_t)(kb + r) * NOUT + nb + tc];
  }
  __syncthreads();
  for (int i = 0; i < 16; i++) {
    int r = (i << 2) + tr;
    Wt[(size_t)(nb + r) * KK2 + kb + tc] = h_bits((_Float16)tile[tc][r]);
  }
}

enum { MODE_OUT = 0, MODE_SIM = 1, MODE_MAIN = 2 };

// C = A (M x K, k-contig) * B^T (rows of B are k-contig), 128x128 tile, 4 waves,
// 16x16x32 f16 MFMA. MODE_SIM: 3-term hi/lo product + packed-key atomic argmax.
// MODE_MAIN: epilogue adds aproj[idx[row]].
template <int MODE>
__global__ __launch_bounds__(256) void gemm_kernel(
    const unsigned short* __restrict__ Ahi, const unsigned short* __restrict__ Alo,
    const unsigned short* __restrict__ Bhi, const unsigned short* __restrict__ Blo,
    int lda, int ldb, int bkoff, int NT,
    float* __restrict__ Dout, int ldd,
    unsigned long long* __restrict__ keys,
    const float* __restrict__ aproj,
    float* __restrict__ out) {
  constexpr int LDK = 40;  // padded leading dim (elements) to spread LDS banks
  constexpr bool SPLIT = (MODE == MODE_SIM);
  __shared__ unsigned short sA[SPLIT ? 2 : 1][128 * LDK];
  __shared__ unsigned short sB[SPLIT ? 2 : 1][128 * LDK];
  int t = threadIdx.x;
  int nt = blockIdx.x % NT, mt = blockIdx.x / NT;
  int mbase = mt << 7, nbase = nt << 7;
  int lane = t & 63, wid = t >> 6;
  int wy = wid >> 1, wx = wid & 1;
  int lr = lane & 15, lk = (lane >> 4) << 3;

  f32x4 zero = {0.f, 0.f, 0.f, 0.f};
  f32x4 acc[4][4];
  for (int i = 0; i < 4; i++)
    for (int j = 0; j < 4; j++) acc[i][j] = zero;

  for (int k0 = 0; k0 < HDIM; k0 += 32) {
    for (int c = t; c < 512; c += 256) {
      int r = c >> 2, ko = (c & 3) << 3;
      size_t ga = (size_t)(mbase + r) * lda + k0 + ko;
      *reinterpret_cast<ushort8v*>(&sA[0][r * LDK + ko]) =
          *reinterpret_cast<const ushort8v*>(Ahi + ga);
      if (SPLIT)
        *reinterpret_cast<ushort8v*>(&sA[1][r * LDK + ko]) =
            *reinterpret_cast<const ushort8v*>(Alo + ga);
      size_t gb = (size_t)(nbase + r) * ldb + bkoff + k0 + ko;
      *reinterpret_cast<ushort8v*>(&sB[0][r * LDK + ko]) =
          *reinterpret_cast<const ushort8v*>(Bhi + gb);
      if (SPLIT)
        *reinterpret_cast<ushort8v*>(&sB[1][r * LDK + ko]) =
            *reinterpret_cast<const ushort8v*>(Blo + gb);
    }
    __syncthreads();
    f16x8 ah[4], bh[4], al[4], bl[4];
    for (int i = 0; i < 4; i++) {
      int ar = (wy << 6) + (i << 4) + lr;
      int br = (wx << 6) + (i << 4) + lr;
      ah[i] = *reinterpret_cast<const f16x8*>(&sA[0][ar * LDK + lk]);
      bh[i] = *reinterpret_cast<const f16x8*>(&sB[0][br * LDK + lk]);
      if (SPLIT) {
        al[i] = *reinterpret_cast<const f16x8*>(&sA[1][ar * LDK + lk]);
        bl[i] = *reinterpret_cast<const f16x8*>(&sB[1][br * LDK + lk]);
      }
    }
    for (int i = 0; i < 4; i++)
      for (int j = 0; j < 4; j++) {
        acc[i][j] = __builtin_amdgcn_mfma_f32_16x16x32_f16(ah[i], bh[j], acc[i][j], 0, 0, 0);
        if (SPLIT) {
          acc[i][j] = __builtin_amdgcn_mfma_f32_16x16x32_f16(ah[i], bl[j], acc[i][j], 0, 0, 0);
          acc[i][j] = __builtin_amdgcn_mfma_f32_16x16x32_f16(al[i], bh[j], acc[i][j], 0, 0, 0);
        }
      }
    __syncthreads();
  }

  int q = lane >> 4, cc = lane & 15;
  if (MODE == MODE_OUT) {
    for (int i = 0; i < 4; i++)
      for (int r = 0; r < 4; r++) {
        int grow = mbase + (wy << 6) + (i << 4) + (q << 2) + r;
        for (int j = 0; j < 4; j++) {
          int gcol = nbase + (wx << 6) + (j << 4) + cc;
          Dout[(size_t)grow * ldd + gcol] = acc[i][j][r];
        }
      }
  } else if (MODE == MODE_SIM) {
    for (int i = 0; i < 4; i++)
      for (int r = 0; r < 4; r++) {
        int grow = mbase + (wy << 6) + (i << 4) + (q << 2) + r;
        unsigned long long best = 0ull;
        for (int j = 0; j < 4; j++) {
          float vv = acc[i][j][r];
          unsigned vb = __float_as_uint(vv);
          vb = (vb & 0x80000000u) ? ~vb : (vb | 0x80000000u);
          unsigned idxn = (unsigned)(nbase + (wx << 6) + (j << 4) + cc);
          unsigned long long key = ((unsigned long long)vb << 32) | (unsigned)(~idxn);
          if (key > best) best = key;
        }
        for (int m = 1; m <= 8; m <<= 1) {
          unsigned long long o = shfl_xor_u64(best, m);
          if (o > best) best = o;
        }
        if (cc == 0) atomicMax(keys + grow, best);
      }
  } else {  // MODE_MAIN
    for (int i = 0; i < 4; i++)
      for (int r = 0; r < 4; r++) {
        int grow = mbase + (wy << 6) + (i << 4) + (q << 2) + r;
        unsigned idx = ~(unsigned)(keys[grow] & 0xFFFFFFFFull);
        idx &= 1023u;  // safety clamp; argmax always lands <1000
        const float* ap = aproj + (size_t)idx * NOUT;
        for (int j = 0; j < 4; j++) {
          int gcol = nbase + (wx << 6) + (j << 4) + cc;
          out[(size_t)grow * NOUT + gcol] = acc[i][j][r] + ap[gcol];
        }
      }
  }
}

extern "C" void kernel_launch(void* const* d_in, const int* in_sizes, int n_in,
                              void* d_out, int out_size, void* d_ws, size_t ws_size,
                              hipStream_t stream) {
  const float* features = (const float*)d_in[0];
  const float* anchors = (const float*)d_in[1];
  const float* Wout = (const float*)d_in[2];
  float* out = (float*)d_out;

  char* p = (char*)d_ws;
  size_t off = 0;
  auto alloc = [&](size_t b) {
    char* r = p + off;
    off += (b + 255) & ~(size_t)255;
    return r;
  };
  unsigned short* fh = (unsigned short*)alloc((size_t)N_ROWS * HDIM * 2);
  unsigned short* fl = (unsigned short*)alloc((size_t)N_ROWS * HDIM * 2);
  unsigned short* ash = (unsigned short*)alloc((size_t)CPAD * HDIM * 2);
  unsigned short* asl = (unsigned short*)alloc((size_t)CPAD * HDIM * 2);
  unsigned short* anh = (unsigned short*)alloc((size_t)CPAD * HDIM * 2);
  unsigned short* wt = (unsigned short*)alloc((size_t)NOUT * KK2 * 2);
  float* ap = (float*)alloc((size_t)CPAD * NOUT * 4);
  unsigned long long* keys = (unsigned long long*)alloc((size_t)N_ROWS * 8);
  if (off > ws_size) return;  // workspace too small; bench will show failure

  init_keys_kernel<<<N_ROWS / 256, 256, 0, stream>>>(keys);
  prep_anchors_kernel<<<CPAD, 256, 0, stream>>>(anchors, ash, asl, anh);
  fsplit_kernel<<<(N_ROWS * HDIM / 4) / 256, 256, 0, stream>>>(features, fh, fl);
  wtrans_kernel<<<512, 256, 0, stream>>>(Wout, wt);
  // anchor_proj = class_anchors @ W[0:1024,:]  -> ap [1024(pad) x 1024] fp32
  gemm_kernel<MODE_OUT><<<64, 256, 0, stream>>>(anh, nullptr, wt, nullptr,
                                                HDIM, KK2, 0, 8, ap, NOUT,
                                                nullptr, nullptr, nullptr);
  // sim + argmax (3-term fp16 split), result packed into keys
  gemm_kernel<MODE_SIM><<<2048, 256, 0, stream>>>(fh, fl, ash, asl,
                                                  HDIM, HDIM, 0, 8, nullptr, 0,
                                                  keys, nullptr, nullptr);
  // out = features @ W[1024:2048,:] + anchor_proj[idx]
  gemm_kernel<MODE_MAIN><<<2048, 256, 0, stream>>>(fh, nullptr, wt, nullptr,
                                                   HDIM, KK2, HDIM, 8, nullptr, 0,
                                                   keys, ap, out);
}